// Round 1
// baseline (468.307 us; speedup 1.0000x reference)
//
#include <hip/hip_runtime.h>

typedef __bf16 bf16;
typedef __attribute__((ext_vector_type(8))) __bf16 bf16x8;
typedef __attribute__((ext_vector_type(4))) __bf16 bf16x4;
typedef __attribute__((ext_vector_type(4))) float f32x4;

#define DEVINL __device__ __forceinline__

// Async global->LDS, 16B per lane. LDS dst must be the wave-uniform base;
// lane l's global data lands at base + l*16.
DEVINL void gload_lds16(const bf16* g, bf16* l) {
    __builtin_amdgcn_global_load_lds(
        (__attribute__((address_space(1))) unsigned int*)(unsigned long long)g,
        (__attribute__((address_space(3))) unsigned int*)l,
        16, 0, 0);
}

// ---------------------------------------------------------------- converts
__global__ __launch_bounds__(256) void cvt_f32_to_bf16(
    const float* __restrict__ in, bf16* __restrict__ out, int n4) {
    int i = blockIdx.x * blockDim.x + threadIdx.x;
    if (i >= n4) return;
    float4 f = ((const float4*)in)[i];
    bf16x4 o;
    o.x = (bf16)f.x; o.y = (bf16)f.y; o.z = (bf16)f.z; o.w = (bf16)f.w;
    ((bf16x4*)out)[i] = o;
}

// ---------------------------------------------------------------- transpose
// [R,C] -> [C,R] bf16 (bit copy), per-batch via blockIdx.z
__global__ __launch_bounds__(256) void transpose_bf16(
    const unsigned short* __restrict__ in, unsigned short* __restrict__ out,
    int R, int C) {
    __shared__ unsigned short t[64][65];
    const size_t bo = (size_t)blockIdx.z * R * C;
    const int r0 = blockIdx.y * 64, c0 = blockIdx.x * 64;
#pragma unroll
    for (int i = 0; i < 16; i++) {
        int lin = threadIdx.x + i * 256;
        int r = lin >> 6, c = lin & 63;
        t[r][c] = in[bo + (size_t)(r0 + r) * C + (c0 + c)];
    }
    __syncthreads();
#pragma unroll
    for (int i = 0; i < 16; i++) {
        int lin = threadIdx.x + i * 256;
        int r = lin >> 6, c = lin & 63;
        out[bo + (size_t)(c0 + r) * R + (r0 + c)] = t[c][r];
    }
}

// ---------------------------------------------------------------- GEMM (B^T)
// C[m,n] = (sum_k A[m,k]*B[n,k]) * scale + bias[n]
// A: [M,K] bf16 row-major, B: [N,K] bf16 row-major.
// EPI 0: bf16 out; EPI 1: f32 out.
// causal 0: none; 1: skip tiles with bx>by (scores); 2: trim K to m0+128 (PV).
// 128x128 tile, BK=32, 4 waves each 64x64 via 4x4 of 16x16x32 MFMA.
template <int EPI>
__global__ __launch_bounds__(256) void gemm_bt(
    const bf16* __restrict__ A, const bf16* __restrict__ B,
    const float* __restrict__ bias, void* __restrict__ Cv,
    int M, int N, int K,
    long long sA, long long sB, long long sC,
    float scale, int causal) {
    const int bx = blockIdx.x, by = blockIdx.y, bz = blockIdx.z;
    if (causal == 1 && bx > by) return;
    const int m0 = by * 128, n0 = bx * 128;
    int Keff = K;
    if (causal == 2) { Keff = m0 + 128; if (Keff > K) Keff = K; }

    A += (size_t)bz * sA;
    B += (size_t)bz * sB;

    __shared__ __align__(16) bf16 As[128 * 32];
    __shared__ __align__(16) bf16 Bs[128 * 32];

    const int tid = threadIdx.x;
    const int wave = tid >> 6;
    const int lane = tid & 63;
    const int lr = lane & 15;   // row-within-16 for frags, col for C
    const int lq = lane >> 4;   // quad
    const int wm = (wave >> 1) * 64;
    const int wn = (wave & 1) * 64;

    // staging geometry: chunk c covers rows [c*16, c*16+16), lane l -> elem l*8
    const int srow = lane >> 2;
    const int scol = (lane & 3) * 8;

    f32x4 acc[4][4];
    const f32x4 fzero = {0.f, 0.f, 0.f, 0.f};
#pragma unroll
    for (int i = 0; i < 4; i++)
#pragma unroll
        for (int j = 0; j < 4; j++) acc[i][j] = fzero;

    for (int k0 = 0; k0 < Keff; k0 += 32) {
        // stage A,B tiles: 8 chunks each of 1KB; wave w does chunks {w, w+4}
        const bf16* ga0 = A + (size_t)(m0 + wave * 16 + srow) * K + (k0 + scol);
        const bf16* gb0 = B + (size_t)(n0 + wave * 16 + srow) * K + (k0 + scol);
        gload_lds16(ga0,                 As + wave * 512);
        gload_lds16(ga0 + (size_t)64 * K, As + (wave + 4) * 512);
        gload_lds16(gb0,                 Bs + wave * 512);
        gload_lds16(gb0 + (size_t)64 * K, Bs + (wave + 4) * 512);
        __syncthreads();

        bf16x8 af[4], bfr[4];
#pragma unroll
        for (int i = 0; i < 4; i++)
            af[i] = *(const bf16x8*)(As + (wm + i * 16 + lr) * 32 + lq * 8);
#pragma unroll
        for (int j = 0; j < 4; j++)
            bfr[j] = *(const bf16x8*)(Bs + (wn + j * 16 + lr) * 32 + lq * 8);
#pragma unroll
        for (int i = 0; i < 4; i++)
#pragma unroll
            for (int j = 0; j < 4; j++)
                acc[i][j] = __builtin_amdgcn_mfma_f32_16x16x32_bf16(
                    af[i], bfr[j], acc[i][j], 0, 0, 0);
        __syncthreads();
    }

    // epilogue: C/D layout col=lane&15, row=quad*4+reg
    if (EPI == 0) {
        bf16* C = (bf16*)Cv + (size_t)bz * sC;
#pragma unroll
        for (int j = 0; j < 4; j++) {
            const int col = n0 + wn + j * 16 + lr;
            const float bb = bias ? bias[col] : 0.0f;
#pragma unroll
            for (int i = 0; i < 4; i++) {
                const int rowb = m0 + wm + i * 16 + lq * 4;
#pragma unroll
                for (int r = 0; r < 4; r++)
                    C[(size_t)(rowb + r) * N + col] =
                        (bf16)(acc[i][j][r] * scale + bb);
            }
        }
    } else {
        float* C = (float*)Cv + (size_t)bz * sC;
#pragma unroll
        for (int j = 0; j < 4; j++) {
            const int col = n0 + wn + j * 16 + lr;
            const float bb = bias ? bias[col] : 0.0f;
#pragma unroll
            for (int i = 0; i < 4; i++) {
                const int rowb = m0 + wm + i * 16 + lq * 4;
#pragma unroll
                for (int r = 0; r < 4; r++)
                    C[(size_t)(rowb + r) * N + col] =
                        acc[i][j][r] * scale + bb;
            }
        }
    }
}

// ---------------------------------------------------------------- softmax
// one block per row; S=2048 = 8*256; causal length L = q+1; bf16 probs out
__global__ __launch_bounds__(256) void softmax_causal(
    const float* __restrict__ Sc, bf16* __restrict__ P, int S) {
    const int row = blockIdx.x;          // b*S + q
    const int q = row & (S - 1);
    const float* src = Sc + (size_t)row * S;
    bf16* dst = P + (size_t)row * S;
    const int L = q + 1;
    const int tid = threadIdx.x;

    float v[8];
    float mx = -3.0e38f;
#pragma unroll
    for (int i = 0; i < 8; i++) {
        int k = tid + i * 256;
        v[i] = (k < L) ? src[k] : -3.0e38f;
        mx = fmaxf(mx, v[i]);
    }
#pragma unroll
    for (int off = 32; off > 0; off >>= 1) mx = fmaxf(mx, __shfl_xor(mx, off, 64));
    __shared__ float redm[4], reds[4];
    if ((tid & 63) == 0) redm[tid >> 6] = mx;
    __syncthreads();
    mx = fmaxf(fmaxf(redm[0], redm[1]), fmaxf(redm[2], redm[3]));

    float sum = 0.f;
#pragma unroll
    for (int i = 0; i < 8; i++) {
        int k = tid + i * 256;
        float e = (k < L) ? __expf(v[i] - mx) : 0.f;
        v[i] = e;
        sum += e;
    }
#pragma unroll
    for (int off = 32; off > 0; off >>= 1) sum += __shfl_xor(sum, off, 64);
    if ((tid & 63) == 0) reds[tid >> 6] = sum;
    __syncthreads();
    sum = reds[0] + reds[1] + reds[2] + reds[3];
    const float inv = 1.0f / sum;
#pragma unroll
    for (int i = 0; i < 8; i++) {
        int k = tid + i * 256;
        dst[k] = (bf16)(v[i] * inv);   // v[i]==0 beyond L -> zeros above diagonal
    }
}

// ---------------------------------------------------------------- launch
extern "C" void kernel_launch(void* const* d_in, const int* in_sizes, int n_in,
                              void* d_out, int out_size, void* d_ws, size_t ws_size,
                              hipStream_t stream) {
    const int B = 4, S = 2048, E = 1024;
    const size_t SBE = (size_t)B * S * E;   // 8,388,608
    const size_t EE = (size_t)E * E;        // 1,048,576

    const float* q_in = (const float*)d_in[0];
    const float* k_in = (const float*)d_in[1];
    const float* v_in = (const float*)d_in[2];
    // d_in[3] = mask (tril) — causality handled by index math
    const float* Wq = (const float*)d_in[4];
    const float* bq = (const float*)d_in[5];
    const float* Wk = (const float*)d_in[6];
    const float* bk = (const float*)d_in[7];
    const float* Wv = (const float*)d_in[8];
    const float* bv = (const float*)d_in[9];
    const float* Wo = (const float*)d_in[10];
    const float* bo = (const float*)d_in[11];

    char* ws = (char*)d_ws;
    // Region A (67,108,864 B), time-multiplexed:
    //   phase 1: qb,kb,vb,Vb (bf16)   phase 2: Sc (fp32, B*S*S)   phase 3: AO (bf16)
    bf16* qb = (bf16*)ws;
    bf16* kb = qb + SBE;
    bf16* vb = kb + SBE;
    bf16* Vb = vb + SBE;
    float* Sc = (float*)ws;
    bf16* AO = (bf16*)ws;
    char* p = ws + 4 * SBE * 2;
    bf16* Qb = (bf16*)p; p += SBE * 2;
    bf16* Kb = (bf16*)p; p += SBE * 2;
    bf16* Vt = (bf16*)p; p += SBE * 2;
    bf16* Pb = (bf16*)p; p += (size_t)B * S * S * 2;
    bf16* Wqb = (bf16*)p; p += EE * 2;
    bf16* Wkb = (bf16*)p; p += EE * 2;
    bf16* Wvb = (bf16*)p; p += EE * 2;
    bf16* Wob = (bf16*)p; p += EE * 2;

    // 1. converts
    cvt_f32_to_bf16<<<(int)(SBE / 4 / 256), 256, 0, stream>>>(q_in, qb, (int)(SBE / 4));
    cvt_f32_to_bf16<<<(int)(SBE / 4 / 256), 256, 0, stream>>>(k_in, kb, (int)(SBE / 4));
    cvt_f32_to_bf16<<<(int)(SBE / 4 / 256), 256, 0, stream>>>(v_in, vb, (int)(SBE / 4));
    cvt_f32_to_bf16<<<(int)(EE / 4 / 256), 256, 0, stream>>>(Wq, Wqb, (int)(EE / 4));
    cvt_f32_to_bf16<<<(int)(EE / 4 / 256), 256, 0, stream>>>(Wk, Wkb, (int)(EE / 4));
    cvt_f32_to_bf16<<<(int)(EE / 4 / 256), 256, 0, stream>>>(Wv, Wvb, (int)(EE / 4));
    cvt_f32_to_bf16<<<(int)(EE / 4 / 256), 256, 0, stream>>>(Wo, Wob, (int)(EE / 4));

    dim3 blk(256);
    // 2. projections: [B*S,E] @ [E,E]^T + bias -> bf16
    dim3 gproj(E / 128, (B * S) / 128, 1);
    gemm_bt<0><<<gproj, blk, 0, stream>>>(qb, Wqb, bq, Qb, B * S, E, E, 0, 0, 0, 1.f, 0);
    gemm_bt<0><<<gproj, blk, 0, stream>>>(kb, Wkb, bk, Kb, B * S, E, E, 0, 0, 0, 1.f, 0);
    gemm_bt<0><<<gproj, blk, 0, stream>>>(vb, Wvb, bv, Vb, B * S, E, E, 0, 0, 0, 1.f, 0);

    // 3. V^T per batch: [S,E] -> [E,S]
    dim3 gt(E / 64, S / 64, B);
    transpose_bf16<<<gt, blk, 0, stream>>>((const unsigned short*)Vb,
                                           (unsigned short*)Vt, S, E);

    // 4. scores = Q K^T / 32, fp32, skip upper-triangle tiles
    dim3 gsc(S / 128, S / 128, B);
    gemm_bt<1><<<gsc, blk, 0, stream>>>(Qb, Kb, nullptr, Sc, S, S, E,
                                        (long long)S * E, (long long)S * E,
                                        (long long)S * S, 0.03125f, 1);

    // 5. causal softmax -> bf16 probs (zeros above diagonal)
    softmax_causal<<<B * S, 256, 0, stream>>>(Sc, Pb, S);

    // 6. AO = P @ V (via Vt), K trimmed causally
    dim3 gpv(E / 128, S / 128, B);
    gemm_bt<0><<<gpv, blk, 0, stream>>>(Pb, Vt, nullptr, AO, S, E, S,
                                        (long long)S * S, (long long)E * S,
                                        (long long)S * E, 1.f, 2);

    // 7. out = AO @ Wo^T + bo, fp32
    gemm_bt<1><<<gproj, blk, 0, stream>>>(AO, Wob, bo, (float*)d_out,
                                          B * S, E, E, 0, 0, 0, 1.f, 0);
}

// Round 2
// 451.832 us; speedup vs baseline: 1.0365x; 1.0365x over previous
//
#include <hip/hip_runtime.h>

typedef __bf16 bf16;
typedef __attribute__((ext_vector_type(8))) __bf16 bf16x8;
typedef __attribute__((ext_vector_type(4))) __bf16 bf16x4;
typedef __attribute__((ext_vector_type(4))) float f32x4;

#define DEVINL __device__ __forceinline__

// Async global->LDS, 16B per lane. LDS dst must be the wave-uniform base;
// lane l's global data lands at base + l*16.
DEVINL void gload_lds16(const bf16* g, bf16* l) {
    __builtin_amdgcn_global_load_lds(
        (__attribute__((address_space(1))) unsigned int*)(unsigned long long)g,
        (__attribute__((address_space(3))) unsigned int*)l,
        16, 0, 0);
}

// ---------------------------------------------------------------- converts
// z selects among up to 3 inputs -> out + z*n4*4 elements
__global__ __launch_bounds__(256) void cvt3_f32_to_bf16(
    const float* __restrict__ a, const float* __restrict__ b,
    const float* __restrict__ c, bf16* __restrict__ out, int n4) {
    int i = blockIdx.x * blockDim.x + threadIdx.x;
    if (i >= n4) return;
    const float* src = (blockIdx.z == 0) ? a : (blockIdx.z == 1) ? b : c;
    bf16* dst = out + (size_t)blockIdx.z * (size_t)n4 * 4;
    float4 f = ((const float4*)src)[i];
    bf16x4 o;
    o.x = (bf16)f.x; o.y = (bf16)f.y; o.z = (bf16)f.z; o.w = (bf16)f.w;
    ((bf16x4*)dst)[i] = o;
}

__global__ __launch_bounds__(256) void cvt4_f32_to_bf16(
    const float* __restrict__ a, const float* __restrict__ b,
    const float* __restrict__ c, const float* __restrict__ d,
    bf16* __restrict__ out, int n4) {
    int i = blockIdx.x * blockDim.x + threadIdx.x;
    if (i >= n4) return;
    const float* src = (blockIdx.z == 0) ? a : (blockIdx.z == 1) ? b
                     : (blockIdx.z == 2) ? c : d;
    bf16* dst = out + (size_t)blockIdx.z * (size_t)n4 * 4;
    float4 f = ((const float4*)src)[i];
    bf16x4 o;
    o.x = (bf16)f.x; o.y = (bf16)f.y; o.z = (bf16)f.z; o.w = (bf16)f.w;
    ((bf16x4*)dst)[i] = o;
}

// ---------------------------------------------------------------- transpose
// [R,C] -> [C,R] bf16 (bit copy), per-batch via blockIdx.z
__global__ __launch_bounds__(256) void transpose_bf16(
    const unsigned short* __restrict__ in, unsigned short* __restrict__ out,
    int R, int C) {
    __shared__ unsigned short t[64][65];
    const size_t bo = (size_t)blockIdx.z * R * C;
    const int r0 = blockIdx.y * 64, c0 = blockIdx.x * 64;
#pragma unroll
    for (int i = 0; i < 16; i++) {
        int lin = threadIdx.x + i * 256;
        int r = lin >> 6, c = lin & 63;
        t[r][c] = in[bo + (size_t)(r0 + r) * C + (c0 + c)];
    }
    __syncthreads();
#pragma unroll
    for (int i = 0; i < 16; i++) {
        int lin = threadIdx.x + i * 256;
        int r = lin >> 6, c = lin & 63;
        out[bo + (size_t)(c0 + r) * R + (r0 + c)] = t[c][r];
    }
}

// ---------------------------------------------------------------- GEMM (B^T)
// C[m,n] = (sum_k A[m,k]*B[n,k]) * scale + bias[n]
// A: [M,K] bf16 row-major, B: [N,K] bf16 row-major.
// EPI 0: bf16 out; EPI 1: f32 out.
// causal 0: none; 1: skip tiles fully above diagonal (scores);
//        2: trim K to m0+128 (PV).
// Tile 128(M) x 64(N), BK=32, 256 threads = 4 waves, each wave 32x64
// via 2x4 of 16x16x32 MFMA. LDS 12 KB -> grids are 2x m97-tile grids,
// which is the point: every GEMM here is grid-starved at 128x128.
template <int EPI>
__global__ __launch_bounds__(256) void gemm_bt(
    const bf16* __restrict__ A, const bf16* __restrict__ B,
    const float* __restrict__ bias, void* __restrict__ Cv,
    int M, int N, int K,
    long long sA, long long sB, long long sC, long long sBias,
    float scale, int causal) {
    const int bx = blockIdx.x, by = blockIdx.y, bz = blockIdx.z;
    const int m0 = by * 128, n0 = bx * 64;
    if (causal == 1 && n0 > m0 + 127) return;
    int Keff = K;
    if (causal == 2) { Keff = m0 + 128; if (Keff > K) Keff = K; }

    A += (size_t)bz * sA;
    B += (size_t)bz * sB;
    if (bias) bias += (size_t)bz * sBias;

    __shared__ __align__(16) bf16 As[128 * 32];
    __shared__ __align__(16) bf16 Bs[64 * 32];

    const int tid = threadIdx.x;
    const int wave = tid >> 6;
    const int lane = tid & 63;
    const int lr = lane & 15;   // row-within-16 for frags, col for C
    const int lq = lane >> 4;   // quad
    const int wm = wave * 32;   // wave's M offset within tile

    // staging geometry: chunk covers 16 rows; lane l -> row l>>2, elems (l&3)*8
    const int srow = lane >> 2;
    const int scol = (lane & 3) * 8;

    f32x4 acc[2][4];
    const f32x4 fzero = {0.f, 0.f, 0.f, 0.f};
#pragma unroll
    for (int i = 0; i < 2; i++)
#pragma unroll
        for (int j = 0; j < 4; j++) acc[i][j] = fzero;

    for (int k0 = 0; k0 < Keff; k0 += 32) {
        // A: 8 chunks of 1KB, wave w stages chunks {w, w+4}; B: 4 chunks, wave w -> w
        const bf16* ga0 = A + (size_t)(m0 + wave * 16 + srow) * K + (k0 + scol);
        const bf16* gb0 = B + (size_t)(n0 + wave * 16 + srow) * K + (k0 + scol);
        gload_lds16(ga0,                  As + wave * 512);
        gload_lds16(ga0 + (size_t)64 * K, As + (wave + 4) * 512);
        gload_lds16(gb0,                  Bs + wave * 512);
        __syncthreads();

        bf16x8 af[2], bfr[4];
#pragma unroll
        for (int i = 0; i < 2; i++)
            af[i] = *(const bf16x8*)(As + (wm + i * 16 + lr) * 32 + lq * 8);
#pragma unroll
        for (int j = 0; j < 4; j++)
            bfr[j] = *(const bf16x8*)(Bs + (j * 16 + lr) * 32 + lq * 8);
#pragma unroll
        for (int i = 0; i < 2; i++)
#pragma unroll
            for (int j = 0; j < 4; j++)
                acc[i][j] = __builtin_amdgcn_mfma_f32_16x16x32_bf16(
                    af[i], bfr[j], acc[i][j], 0, 0, 0);
        __syncthreads();
    }

    // epilogue: C/D layout col=lane&15, row=quad*4+reg
    if (EPI == 0) {
        bf16* C = (bf16*)Cv + (size_t)bz * sC;
#pragma unroll
        for (int j = 0; j < 4; j++) {
            const int col = n0 + j * 16 + lr;
            const float bb = bias ? bias[col] : 0.0f;
#pragma unroll
            for (int i = 0; i < 2; i++) {
                const int rowb = m0 + wm + i * 16 + lq * 4;
#pragma unroll
                for (int r = 0; r < 4; r++)
                    C[(size_t)(rowb + r) * N + col] =
                        (bf16)(acc[i][j][r] * scale + bb);
            }
        }
    } else {
        float* C = (float*)Cv + (size_t)bz * sC;
#pragma unroll
        for (int j = 0; j < 4; j++) {
            const int col = n0 + j * 16 + lr;
            const float bb = bias ? bias[col] : 0.0f;
#pragma unroll
            for (int i = 0; i < 2; i++) {
                const int rowb = m0 + wm + i * 16 + lq * 4;
#pragma unroll
                for (int r = 0; r < 4; r++)
                    C[(size_t)(rowb + r) * N + col] =
                        acc[i][j][r] * scale + bb;
            }
        }
    }
}

// ---------------------------------------------------------------- softmax
// one block per row; S=2048 = 8*256; causal length L = q+1; bf16 probs out
__global__ __launch_bounds__(256) void softmax_causal(
    const float* __restrict__ Sc, bf16* __restrict__ P, int S) {
    const int row = blockIdx.x;          // b*S + q
    const int q = row & (S - 1);
    const float* src = Sc + (size_t)row * S;
    bf16* dst = P + (size_t)row * S;
    const int L = q + 1;
    const int tid = threadIdx.x;

    float v[8];
    float mx = -3.0e38f;
#pragma unroll
    for (int i = 0; i < 8; i++) {
        int k = tid + i * 256;
        v[i] = (k < L) ? src[k] : -3.0e38f;
        mx = fmaxf(mx, v[i]);
    }
#pragma unroll
    for (int off = 32; off > 0; off >>= 1) mx = fmaxf(mx, __shfl_xor(mx, off, 64));
    __shared__ float redm[4], reds[4];
    if ((tid & 63) == 0) redm[tid >> 6] = mx;
    __syncthreads();
    mx = fmaxf(fmaxf(redm[0], redm[1]), fmaxf(redm[2], redm[3]));

    float sum = 0.f;
#pragma unroll
    for (int i = 0; i < 8; i++) {
        int k = tid + i * 256;
        float e = (k < L) ? __expf(v[i] - mx) : 0.f;
        v[i] = e;
        sum += e;
    }
#pragma unroll
    for (int off = 32; off > 0; off >>= 1) sum += __shfl_xor(sum, off, 64);
    if ((tid & 63) == 0) reds[tid >> 6] = sum;
    __syncthreads();
    sum = reds[0] + reds[1] + reds[2] + reds[3];
    const float inv = 1.0f / sum;
#pragma unroll
    for (int i = 0; i < 8; i++) {
        int k = tid + i * 256;
        dst[k] = (bf16)(v[i] * inv);   // v[i]==0 beyond L -> zeros above diagonal
    }
}

// ---------------------------------------------------------------- launch
extern "C" void kernel_launch(void* const* d_in, const int* in_sizes, int n_in,
                              void* d_out, int out_size, void* d_ws, size_t ws_size,
                              hipStream_t stream) {
    const int B = 4, S = 2048, E = 1024;
    const size_t SBE = (size_t)B * S * E;   // 8,388,608
    const size_t EE = (size_t)E * E;        // 1,048,576

    const float* q_in = (const float*)d_in[0];
    const float* k_in = (const float*)d_in[1];
    const float* v_in = (const float*)d_in[2];
    // d_in[3] = mask (tril) — causality handled by index math
    const float* Wq = (const float*)d_in[4];
    const float* bq = (const float*)d_in[5];
    const float* Wk = (const float*)d_in[6];
    const float* bk = (const float*)d_in[7];
    const float* Wv = (const float*)d_in[8];
    const float* bv = (const float*)d_in[9];
    const float* Wo = (const float*)d_in[10];
    const float* bo = (const float*)d_in[11];

    char* ws = (char*)d_ws;
    // Region A (67,108,864 B), time-multiplexed:
    //   phase 1: qb,kb,vb (bf16, 48MB)  phase 2: Sc (fp32, B*S*S)  phase 3: AO (bf16)
    bf16* qkvb = (bf16*)ws;       // qb|kb|vb contiguous, stride SBE
    float* Sc = (float*)ws;
    bf16* AO = (bf16*)ws;
    char* p = ws + (size_t)B * S * S * 4;   // 67MB
    bf16* QKVb = (bf16*)p; p += 3 * SBE * 2;   // Qb|Kb|Vb contiguous
    bf16* Vt = (bf16*)p; p += SBE * 2;
    bf16* Pb = (bf16*)p; p += (size_t)B * S * S * 2;
    bf16* Wb = (bf16*)p; p += 4 * EE * 2;      // Wq|Wk|Wv|Wo contiguous
    float* biasWS = (float*)p; p += 3 * E * 4; // bq|bk|bv contiguous

    bf16* Qb = QKVb;
    bf16* Vb = QKVb + 2 * SBE;
    bf16* Wob = Wb + 3 * EE;

    // 1. converts (2 dispatches) + bias gather (3 tiny d2d copies)
    dim3 gcvt3((int)(SBE / 4 / 256), 1, 3);
    cvt3_f32_to_bf16<<<gcvt3, 256, 0, stream>>>(q_in, k_in, v_in, qkvb, (int)(SBE / 4));
    dim3 gcvt4((int)(EE / 4 / 256), 1, 4);
    cvt4_f32_to_bf16<<<gcvt4, 256, 0, stream>>>(Wq, Wk, Wv, Wo, Wb, (int)(EE / 4));
    hipMemcpyAsync(biasWS,         bq, E * 4, hipMemcpyDeviceToDevice, stream);
    hipMemcpyAsync(biasWS + E,     bk, E * 4, hipMemcpyDeviceToDevice, stream);
    hipMemcpyAsync(biasWS + 2 * E, bv, E * 4, hipMemcpyDeviceToDevice, stream);

    dim3 blk(256);
    // 2. fused QKV projection: z in {0,1,2}: [B*S,E] @ W^T + bias -> bf16
    dim3 gproj(E / 64, (B * S) / 128, 3);
    gemm_bt<0><<<gproj, blk, 0, stream>>>(qkvb, Wb, biasWS, QKVb,
                                          B * S, E, E,
                                          (long long)SBE, (long long)EE,
                                          (long long)SBE, (long long)E, 1.f, 0);

    // 3. V^T per batch: [S,E] -> [E,S]
    dim3 gt(E / 64, S / 64, B);
    transpose_bf16<<<gt, blk, 0, stream>>>((const unsigned short*)Vb,
                                           (unsigned short*)Vt, S, E);

    // 4. scores = Q K^T / 32, fp32, skip tiles above the diagonal
    dim3 gsc(S / 64, S / 128, B);
    gemm_bt<1><<<gsc, blk, 0, stream>>>(Qb, QKVb + SBE, nullptr, Sc, S, S, E,
                                        (long long)S * E, (long long)S * E,
                                        (long long)S * S, 0, 0.03125f, 1);

    // 5. causal softmax -> bf16 probs (zeros above diagonal)
    softmax_causal<<<B * S, 256, 0, stream>>>(Sc, Pb, S);

    // 6. AO = P @ V (via Vt), K trimmed causally
    dim3 gpv(E / 64, S / 128, B);
    gemm_bt<0><<<gpv, blk, 0, stream>>>(Pb, Vt, nullptr, AO, S, E, S,
                                        (long long)S * S, (long long)E * S,
                                        (long long)S * E, 0, 1.f, 2);

    // 7. out = AO @ Wo^T + bo, fp32
    dim3 gout(E / 64, (B * S) / 128, 1);
    gemm_bt<1><<<gout, blk, 0, stream>>>(AO, Wob, bo, (float*)d_out,
                                         B * S, E, E, 0, 0, 0, 0, 1.f, 0);
}

// Round 3
// 431.729 us; speedup vs baseline: 1.0847x; 1.0466x over previous
//
#include <hip/hip_runtime.h>

typedef __bf16 bf16;
typedef __attribute__((ext_vector_type(8))) __bf16 bf16x8;
typedef __attribute__((ext_vector_type(4))) __bf16 bf16x4;
typedef __attribute__((ext_vector_type(4))) float f32x4;

#define DEVINL __device__ __forceinline__

// Async global->LDS, 16B per lane. LDS dst must be the wave-uniform base;
// lane l's global data lands at base + l*16.
DEVINL void gload_lds16(const bf16* g, bf16* l) {
    __builtin_amdgcn_global_load_lds(
        (__attribute__((address_space(1))) unsigned int*)(unsigned long long)g,
        (__attribute__((address_space(3))) unsigned int*)l,
        16, 0, 0);
}

// ---------------------------------------------------------------- converts
__global__ __launch_bounds__(256) void cvt3_f32_to_bf16(
    const float* __restrict__ a, const float* __restrict__ b,
    const float* __restrict__ c, bf16* __restrict__ out, int n4) {
    int i = blockIdx.x * blockDim.x + threadIdx.x;
    if (i >= n4) return;
    const float* src = (blockIdx.z == 0) ? a : (blockIdx.z == 1) ? b : c;
    bf16* dst = out + (size_t)blockIdx.z * (size_t)n4 * 4;
    float4 f = ((const float4*)src)[i];
    bf16x4 o;
    o.x = (bf16)f.x; o.y = (bf16)f.y; o.z = (bf16)f.z; o.w = (bf16)f.w;
    ((bf16x4*)dst)[i] = o;
}

__global__ __launch_bounds__(256) void cvt4_f32_to_bf16(
    const float* __restrict__ a, const float* __restrict__ b,
    const float* __restrict__ c, const float* __restrict__ d,
    bf16* __restrict__ out, int n4) {
    int i = blockIdx.x * blockDim.x + threadIdx.x;
    if (i >= n4) return;
    const float* src = (blockIdx.z == 0) ? a : (blockIdx.z == 1) ? b
                     : (blockIdx.z == 2) ? c : d;
    bf16* dst = out + (size_t)blockIdx.z * (size_t)n4 * 4;
    float4 f = ((const float4*)src)[i];
    bf16x4 o;
    o.x = (bf16)f.x; o.y = (bf16)f.y; o.z = (bf16)f.z; o.w = (bf16)f.w;
    ((bf16x4*)dst)[i] = o;
}

// ---------------------------------------------------------------- transpose
__global__ __launch_bounds__(256) void transpose_bf16(
    const unsigned short* __restrict__ in, unsigned short* __restrict__ out,
    int R, int C) {
    __shared__ unsigned short t[64][65];
    const size_t bo = (size_t)blockIdx.z * R * C;
    const int r0 = blockIdx.y * 64, c0 = blockIdx.x * 64;
#pragma unroll
    for (int i = 0; i < 16; i++) {
        int lin = threadIdx.x + i * 256;
        int r = lin >> 6, c = lin & 63;
        t[r][c] = in[bo + (size_t)(r0 + r) * C + (c0 + c)];
    }
    __syncthreads();
#pragma unroll
    for (int i = 0; i < 16; i++) {
        int lin = threadIdx.x + i * 256;
        int r = lin >> 6, c = lin & 63;
        out[bo + (size_t)(c0 + r) * R + (r0 + c)] = t[c][r];
    }
}

// ------------------------------------------------- GEMM 128x128, BK=32 (m97)
// C[m,n] = (sum_k A[m,k]*B[n,k]) * scale + bias[n].  For big grids (>=4/CU).
template <int EPI>
__global__ __launch_bounds__(256) void gemm_bt128(
    const bf16* __restrict__ A, const bf16* __restrict__ B,
    const float* __restrict__ bias, void* __restrict__ Cv,
    int M, int N, int K,
    long long sA, long long sB, long long sC, long long sBias,
    float scale) {
    const int bx = blockIdx.x, by = blockIdx.y, bz = blockIdx.z;
    const int m0 = by * 128, n0 = bx * 128;

    A += (size_t)bz * sA;
    B += (size_t)bz * sB;
    if (bias) bias += (size_t)bz * sBias;

    __shared__ __align__(16) bf16 As[128 * 32];
    __shared__ __align__(16) bf16 Bs[128 * 32];

    const int tid = threadIdx.x;
    const int wave = tid >> 6;
    const int lane = tid & 63;
    const int lr = lane & 15;
    const int lq = lane >> 4;
    const int wm = (wave >> 1) * 64;
    const int wn = (wave & 1) * 64;
    const int srow = lane >> 2;
    const int scol = (lane & 3) * 8;

    f32x4 acc[4][4];
    const f32x4 fzero = {0.f, 0.f, 0.f, 0.f};
#pragma unroll
    for (int i = 0; i < 4; i++)
#pragma unroll
        for (int j = 0; j < 4; j++) acc[i][j] = fzero;

    for (int k0 = 0; k0 < K; k0 += 32) {
        const bf16* ga0 = A + (size_t)(m0 + wave * 16 + srow) * K + (k0 + scol);
        const bf16* gb0 = B + (size_t)(n0 + wave * 16 + srow) * K + (k0 + scol);
        gload_lds16(ga0,                  As + wave * 512);
        gload_lds16(ga0 + (size_t)64 * K, As + (wave + 4) * 512);
        gload_lds16(gb0,                  Bs + wave * 512);
        gload_lds16(gb0 + (size_t)64 * K, Bs + (wave + 4) * 512);
        __syncthreads();

        bf16x8 af[4], bfr[4];
#pragma unroll
        for (int i = 0; i < 4; i++)
            af[i] = *(const bf16x8*)(As + (wm + i * 16 + lr) * 32 + lq * 8);
#pragma unroll
        for (int j = 0; j < 4; j++)
            bfr[j] = *(const bf16x8*)(Bs + (wn + j * 16 + lr) * 32 + lq * 8);
#pragma unroll
        for (int i = 0; i < 4; i++)
#pragma unroll
            for (int j = 0; j < 4; j++)
                acc[i][j] = __builtin_amdgcn_mfma_f32_16x16x32_bf16(
                    af[i], bfr[j], acc[i][j], 0, 0, 0);
        __syncthreads();
    }

#pragma unroll
    for (int j = 0; j < 4; j++) {
        const int col = n0 + wn + j * 16 + lr;
        const float bb = bias ? bias[col] : 0.0f;
#pragma unroll
        for (int i = 0; i < 4; i++) {
            const int rowb = m0 + wm + i * 16 + lq * 4;
#pragma unroll
            for (int r = 0; r < 4; r++) {
                if (EPI == 0)
                    ((bf16*)Cv)[(size_t)bz * sC + (size_t)(rowb + r) * N + col] =
                        (bf16)(acc[i][j][r] * scale + bb);
                else
                    ((float*)Cv)[(size_t)bz * sC + (size_t)(rowb + r) * N + col] =
                        acc[i][j][r] * scale + bb;
            }
        }
    }
}

// ------------------------------------------------- GEMM 128x64, BK=64
// Two BK=32 sub-tiles per barrier (preserves global_load_lds lane contiguity
// and the benign 4-way frag-read layout; halves barrier count vs BK=32).
// causal 1: skip tiles fully above diagonal; 2: trim K to m0+128 (PV).
template <int EPI>
__global__ __launch_bounds__(256) void gemm_bt64(
    const bf16* __restrict__ A, const bf16* __restrict__ B,
    const float* __restrict__ bias, void* __restrict__ Cv,
    int M, int N, int K,
    long long sA, long long sB, long long sC, long long sBias,
    float scale, int causal) {
    const int bx = blockIdx.x, by = blockIdx.y, bz = blockIdx.z;
    const int m0 = by * 128, n0 = bx * 64;
    if (causal == 1 && n0 > m0 + 127) return;
    int Keff = K;
    if (causal == 2) { Keff = m0 + 128; if (Keff > K) Keff = K; }

    A += (size_t)bz * sA;
    B += (size_t)bz * sB;
    if (bias) bias += (size_t)bz * sBias;

    __shared__ __align__(16) bf16 As[2][128 * 32];
    __shared__ __align__(16) bf16 Bs[2][64 * 32];

    const int tid = threadIdx.x;
    const int wave = tid >> 6;
    const int lane = tid & 63;
    const int lr = lane & 15;
    const int lq = lane >> 4;
    const int wm = wave * 32;
    const int srow = lane >> 2;
    const int scol = (lane & 3) * 8;

    f32x4 acc[2][4];
    const f32x4 fzero = {0.f, 0.f, 0.f, 0.f};
#pragma unroll
    for (int i = 0; i < 2; i++)
#pragma unroll
        for (int j = 0; j < 4; j++) acc[i][j] = fzero;

    for (int k0 = 0; k0 < Keff; k0 += 64) {
#pragma unroll
        for (int kc = 0; kc < 2; kc++) {
            const bf16* ga0 =
                A + (size_t)(m0 + wave * 16 + srow) * K + (k0 + kc * 32 + scol);
            const bf16* gb0 =
                B + (size_t)(n0 + wave * 16 + srow) * K + (k0 + kc * 32 + scol);
            gload_lds16(ga0,                  As[kc] + wave * 512);
            gload_lds16(ga0 + (size_t)64 * K, As[kc] + (wave + 4) * 512);
            gload_lds16(gb0,                  Bs[kc] + wave * 512);
        }
        __syncthreads();

        bf16x8 af[2][2], bfr[2][4];
#pragma unroll
        for (int kc = 0; kc < 2; kc++) {
#pragma unroll
            for (int i = 0; i < 2; i++)
                af[kc][i] = *(const bf16x8*)(As[kc] + (wm + i * 16 + lr) * 32 + lq * 8);
#pragma unroll
            for (int j = 0; j < 4; j++)
                bfr[kc][j] = *(const bf16x8*)(Bs[kc] + (j * 16 + lr) * 32 + lq * 8);
        }
#pragma unroll
        for (int kc = 0; kc < 2; kc++)
#pragma unroll
            for (int i = 0; i < 2; i++)
#pragma unroll
                for (int j = 0; j < 4; j++)
                    acc[i][j] = __builtin_amdgcn_mfma_f32_16x16x32_bf16(
                        af[kc][i], bfr[kc][j], acc[i][j], 0, 0, 0);
        __syncthreads();
    }

#pragma unroll
    for (int j = 0; j < 4; j++) {
        const int col = n0 + j * 16 + lr;
        const float bb = bias ? bias[col] : 0.0f;
#pragma unroll
        for (int i = 0; i < 2; i++) {
            const int rowb = m0 + wm + i * 16 + lq * 4;
#pragma unroll
            for (int r = 0; r < 4; r++) {
                if (EPI == 0)
                    ((bf16*)Cv)[(size_t)bz * sC + (size_t)(rowb + r) * N + col] =
                        (bf16)(acc[i][j][r] * scale + bb);
                else
                    ((float*)Cv)[(size_t)bz * sC + (size_t)(rowb + r) * N + col] =
                        acc[i][j][r] * scale + bb;
            }
        }
    }
}

// ---------------------------------------------------------------- softmax
// one block per row; S=2048 = 8*256; causal length L = q+1; bf16 probs out
__global__ __launch_bounds__(256) void softmax_causal(
    const float* __restrict__ Sc, bf16* __restrict__ P, int S) {
    const int row = blockIdx.x;          // b*S + q
    const int q = row & (S - 1);
    const float* src = Sc + (size_t)row * S;
    bf16* dst = P + (size_t)row * S;
    const int L = q + 1;
    const int tid = threadIdx.x;

    float v[8];
    float mx = -3.0e38f;
#pragma unroll
    for (int i = 0; i < 8; i++) {
        int k = tid + i * 256;
        v[i] = (k < L) ? src[k] : -3.0e38f;
        mx = fmaxf(mx, v[i]);
    }
#pragma unroll
    for (int off = 32; off > 0; off >>= 1) mx = fmaxf(mx, __shfl_xor(mx, off, 64));
    __shared__ float redm[4], reds[4];
    if ((tid & 63) == 0) redm[tid >> 6] = mx;
    __syncthreads();
    mx = fmaxf(fmaxf(redm[0], redm[1]), fmaxf(redm[2], redm[3]));

    float sum = 0.f;
#pragma unroll
    for (int i = 0; i < 8; i++) {
        int k = tid + i * 256;
        float e = (k < L) ? __expf(v[i] - mx) : 0.f;
        v[i] = e;
        sum += e;
    }
#pragma unroll
    for (int off = 32; off > 0; off >>= 1) sum += __shfl_xor(sum, off, 64);
    if ((tid & 63) == 0) reds[tid >> 6] = sum;
    __syncthreads();
    sum = reds[0] + reds[1] + reds[2] + reds[3];
    const float inv = 1.0f / sum;
#pragma unroll
    for (int i = 0; i < 8; i++) {
        int k = tid + i * 256;
        dst[k] = (bf16)(v[i] * inv);
    }
}

// ---------------------------------------------------------------- launch
extern "C" void kernel_launch(void* const* d_in, const int* in_sizes, int n_in,
                              void* d_out, int out_size, void* d_ws, size_t ws_size,
                              hipStream_t stream) {
    const int B = 4, S = 2048, E = 1024;
    const size_t SBE = (size_t)B * S * E;   // 8,388,608
    const size_t EE = (size_t)E * E;        // 1,048,576

    const float* q_in = (const float*)d_in[0];
    const float* k_in = (const float*)d_in[1];
    const float* v_in = (const float*)d_in[2];
    // d_in[3] = mask (tril) — causality handled by index math
    const float* Wq = (const float*)d_in[4];
    const float* bq = (const float*)d_in[5];
    const float* Wk = (const float*)d_in[6];
    const float* bk = (const float*)d_in[7];
    const float* Wv = (const float*)d_in[8];
    const float* bv = (const float*)d_in[9];
    const float* Wo = (const float*)d_in[10];
    const float* bo = (const float*)d_in[11];

    char* ws = (char*)d_ws;
    // Region A, time-multiplexed:
    //   phase 1: qb|kb|vb (bf16, 48MB)  phase 2: Sc (fp32)  phase 3: AO (bf16)
    bf16* qkvb = (bf16*)ws;
    float* Sc = (float*)ws;
    bf16* AO = (bf16*)ws;
    char* p = ws + (size_t)B * S * S * 4;
    bf16* QKVb = (bf16*)p; p += 3 * SBE * 2;   // Qb|Kb|Vb contiguous
    bf16* Vt = (bf16*)p; p += SBE * 2;
    bf16* Pb = (bf16*)p; p += (size_t)B * S * S * 2;
    bf16* Wb = (bf16*)p; p += 4 * EE * 2;      // Wq|Wk|Wv|Wo contiguous
    float* biasWS = (float*)p; p += 3 * E * 4; // bq|bk|bv contiguous

    bf16* Qb = QKVb;
    bf16* Vb = QKVb + 2 * SBE;
    bf16* Wob = Wb + 3 * EE;

    // 1. converts + bias gather
    dim3 gcvt3((int)(SBE / 4 / 256), 1, 3);
    cvt3_f32_to_bf16<<<gcvt3, 256, 0, stream>>>(q_in, k_in, v_in, qkvb, (int)(SBE / 4));
    dim3 gcvt4((int)(EE / 4 / 256), 1, 4);
    cvt4_f32_to_bf16<<<gcvt4, 256, 0, stream>>>(Wq, Wk, Wv, Wo, Wb, (int)(EE / 4));
    hipMemcpyAsync(biasWS,         bq, E * 4, hipMemcpyDeviceToDevice, stream);
    hipMemcpyAsync(biasWS + E,     bk, E * 4, hipMemcpyDeviceToDevice, stream);
    hipMemcpyAsync(biasWS + 2 * E, bv, E * 4, hipMemcpyDeviceToDevice, stream);

    dim3 blk(256);
    // 2. fused QKV projection, 128x128 tiles: 1536 blocks (6/CU)
    dim3 gproj(E / 128, (B * S) / 128, 3);
    gemm_bt128<0><<<gproj, blk, 0, stream>>>(qkvb, Wb, biasWS, QKVb,
                                             B * S, E, E,
                                             (long long)SBE, (long long)EE,
                                             (long long)SBE, (long long)E, 1.f);

    // 3. V^T per batch: [S,E] -> [E,S]
    dim3 gt(E / 64, S / 64, B);
    transpose_bf16<<<gt, blk, 0, stream>>>((const unsigned short*)Vb,
                                           (unsigned short*)Vt, S, E);

    // 4. scores = Q K^T / 32, fp32, skip tiles above diagonal (1088 live blocks)
    dim3 gsc(S / 64, S / 128, B);
    gemm_bt64<1><<<gsc, blk, 0, stream>>>(Qb, QKVb + SBE, nullptr, Sc, S, S, E,
                                          (long long)S * E, (long long)S * E,
                                          (long long)S * S, 0, 0.03125f, 1);

    // 5. causal softmax -> bf16 probs (zeros above diagonal)
    softmax_causal<<<B * S, 256, 0, stream>>>(Sc, Pb, S);

    // 6. AO = P @ V (via Vt), K trimmed causally (1024 blocks)
    dim3 gpv(E / 64, S / 128, B);
    gemm_bt64<0><<<gpv, blk, 0, stream>>>(Pb, Vt, nullptr, AO, S, E, S,
                                          (long long)S * S, (long long)E * S,
                                          (long long)S * E, 0, 1.f, 2);

    // 7. out = AO @ Wo^T + bo, fp32 (1024 blocks)
    dim3 gout(E / 64, (B * S) / 128, 1);
    gemm_bt64<1><<<gout, blk, 0, stream>>>(AO, Wob, bo, (float*)d_out,
                                           B * S, E, E, 0, 0, 0, 0, 1.f, 0);
}

// Round 4
// 421.668 us; speedup vs baseline: 1.1106x; 1.0239x over previous
//
#include <hip/hip_runtime.h>

typedef __bf16 bf16;
typedef __attribute__((ext_vector_type(8))) __bf16 bf16x8;
typedef __attribute__((ext_vector_type(4))) __bf16 bf16x4;
typedef __attribute__((ext_vector_type(2))) __bf16 bf16x2;
typedef __attribute__((ext_vector_type(4))) float f32x4;

#define DEVINL __device__ __forceinline__

// Async global->LDS, 16B per lane. LDS dst must be the wave-uniform base;
// lane l's global data lands at base + l*16.
DEVINL void gload_lds16(const bf16* g, bf16* l) {
    __builtin_amdgcn_global_load_lds(
        (__attribute__((address_space(1))) unsigned int*)(unsigned long long)g,
        (__attribute__((address_space(3))) unsigned int*)l,
        16, 0, 0);
}

// XCD-aware swizzle: block->XCD is (linear id % 8). Give each XCD a
// contiguous by-slab with bx fastest so same-A blocks share one L2.
// Requires gridDim.y % 8 == 0.
DEVINL void xcd_swizzle(int& bx, int& by) {
    const int gx = gridDim.x, gy = gridDim.y;
    const int l = blockIdx.y * gx + blockIdx.x;
    const int xcd = l & 7;
    const int li = l >> 3;
    by = xcd * (gy >> 3) + li / gx;
    bx = li - (li / gx) * gx;
}

// ---------------------------------------------------------------- converts
__global__ __launch_bounds__(256) void cvt3_f32_to_bf16(
    const float* __restrict__ a, const float* __restrict__ b,
    const float* __restrict__ c, bf16* __restrict__ out, int n4) {
    int i = blockIdx.x * blockDim.x + threadIdx.x;
    if (i >= n4) return;
    const float* src = (blockIdx.z == 0) ? a : (blockIdx.z == 1) ? b : c;
    bf16* dst = out + (size_t)blockIdx.z * (size_t)n4 * 4;
    float4 f = ((const float4*)src)[i];
    bf16x4 o;
    o.x = (bf16)f.x; o.y = (bf16)f.y; o.z = (bf16)f.z; o.w = (bf16)f.w;
    ((bf16x4*)dst)[i] = o;
}

__global__ __launch_bounds__(256) void cvt4_f32_to_bf16(
    const float* __restrict__ a, const float* __restrict__ b,
    const float* __restrict__ c, const float* __restrict__ d,
    bf16* __restrict__ out, int n4) {
    int i = blockIdx.x * blockDim.x + threadIdx.x;
    if (i >= n4) return;
    const float* src = (blockIdx.z == 0) ? a : (blockIdx.z == 1) ? b
                     : (blockIdx.z == 2) ? c : d;
    bf16* dst = out + (size_t)blockIdx.z * (size_t)n4 * 4;
    float4 f = ((const float4*)src)[i];
    bf16x4 o;
    o.x = (bf16)f.x; o.y = (bf16)f.y; o.z = (bf16)f.z; o.w = (bf16)f.w;
    ((bf16x4*)dst)[i] = o;
}

// ---------------------------------------------------------------- transpose
__global__ __launch_bounds__(256) void transpose_bf16(
    const unsigned short* __restrict__ in, unsigned short* __restrict__ out,
    int R, int C) {
    __shared__ unsigned short t[64][65];
    const size_t bo = (size_t)blockIdx.z * R * C;
    const int r0 = blockIdx.y * 64, c0 = blockIdx.x * 64;
#pragma unroll
    for (int i = 0; i < 16; i++) {
        int lin = threadIdx.x + i * 256;
        int r = lin >> 6, c = lin & 63;
        t[r][c] = in[bo + (size_t)(r0 + r) * C + (c0 + c)];
    }
    __syncthreads();
#pragma unroll
    for (int i = 0; i < 16; i++) {
        int lin = threadIdx.x + i * 256;
        int r = lin >> 6, c = lin & 63;
        out[bo + (size_t)(c0 + r) * R + (r0 + c)] = t[c][r];
    }
}

// ------------------------------------------------- GEMM 128x128, BK=32 (m97)
template <int EPI>
__global__ __launch_bounds__(256) void gemm_bt128(
    const bf16* __restrict__ A, const bf16* __restrict__ B,
    const float* __restrict__ bias, void* __restrict__ Cv,
    int M, int N, int K,
    long long sA, long long sB, long long sC, long long sBias,
    float scale) {
    int bx, by;
    xcd_swizzle(bx, by);
    const int bz = blockIdx.z;
    const int m0 = by * 128, n0 = bx * 128;

    A += (size_t)bz * sA;
    B += (size_t)bz * sB;
    if (bias) bias += (size_t)bz * sBias;

    __shared__ __align__(16) bf16 As[128 * 32];
    __shared__ __align__(16) bf16 Bs[128 * 32];

    const int tid = threadIdx.x;
    const int wave = tid >> 6;
    const int lane = tid & 63;
    const int lr = lane & 15;
    const int lq = lane >> 4;
    const int wm = (wave >> 1) * 64;
    const int wn = (wave & 1) * 64;
    const int srow = lane >> 2;
    const int scol = (lane & 3) * 8;

    f32x4 acc[4][4];
    const f32x4 fzero = {0.f, 0.f, 0.f, 0.f};
#pragma unroll
    for (int i = 0; i < 4; i++)
#pragma unroll
        for (int j = 0; j < 4; j++) acc[i][j] = fzero;

    for (int k0 = 0; k0 < K; k0 += 32) {
        const bf16* ga0 = A + (size_t)(m0 + wave * 16 + srow) * K + (k0 + scol);
        const bf16* gb0 = B + (size_t)(n0 + wave * 16 + srow) * K + (k0 + scol);
        gload_lds16(ga0,                  As + wave * 512);
        gload_lds16(ga0 + (size_t)64 * K, As + (wave + 4) * 512);
        gload_lds16(gb0,                  Bs + wave * 512);
        gload_lds16(gb0 + (size_t)64 * K, Bs + (wave + 4) * 512);
        __syncthreads();

        bf16x8 af[4], bfr[4];
#pragma unroll
        for (int i = 0; i < 4; i++)
            af[i] = *(const bf16x8*)(As + (wm + i * 16 + lr) * 32 + lq * 8);
#pragma unroll
        for (int j = 0; j < 4; j++)
            bfr[j] = *(const bf16x8*)(Bs + (wn + j * 16 + lr) * 32 + lq * 8);
#pragma unroll
        for (int i = 0; i < 4; i++)
#pragma unroll
            for (int j = 0; j < 4; j++)
                acc[i][j] = __builtin_amdgcn_mfma_f32_16x16x32_bf16(
                    af[i], bfr[j], acc[i][j], 0, 0, 0);
        __syncthreads();
    }

#pragma unroll
    for (int j = 0; j < 4; j++) {
        const int col = n0 + wn + j * 16 + lr;
        const float bb = bias ? bias[col] : 0.0f;
#pragma unroll
        for (int i = 0; i < 4; i++) {
            const int rowb = m0 + wm + i * 16 + lq * 4;
#pragma unroll
            for (int r = 0; r < 4; r++) {
                if (EPI == 0)
                    ((bf16*)Cv)[(size_t)bz * sC + (size_t)(rowb + r) * N + col] =
                        (bf16)(acc[i][j][r] * scale + bb);
                else
                    ((float*)Cv)[(size_t)bz * sC + (size_t)(rowb + r) * N + col] =
                        acc[i][j][r] * scale + bb;
            }
        }
    }
}

// ------------------------------------------------- GEMM 128x64, BK=64
// causal 1: skip tiles fully above diagonal; 2: trim K to m0+128 (PV).
template <int EPI>
__global__ __launch_bounds__(256) void gemm_bt64(
    const bf16* __restrict__ A, const bf16* __restrict__ B,
    const float* __restrict__ bias, void* __restrict__ Cv,
    int M, int N, int K,
    long long sA, long long sB, long long sC, long long sBias,
    float scale, int causal) {
    int bx, by;
    xcd_swizzle(bx, by);
    const int bz = blockIdx.z;
    const int m0 = by * 128, n0 = bx * 64;
    if (causal == 1 && n0 > m0 + 127) return;
    int Keff = K;
    if (causal == 2) { Keff = m0 + 128; if (Keff > K) Keff = K; }

    A += (size_t)bz * sA;
    B += (size_t)bz * sB;
    if (bias) bias += (size_t)bz * sBias;

    __shared__ __align__(16) bf16 As[2][128 * 32];
    __shared__ __align__(16) bf16 Bs[2][64 * 32];

    const int tid = threadIdx.x;
    const int wave = tid >> 6;
    const int lane = tid & 63;
    const int lr = lane & 15;
    const int lq = lane >> 4;
    const int wm = wave * 32;
    const int srow = lane >> 2;
    const int scol = (lane & 3) * 8;

    f32x4 acc[2][4];
    const f32x4 fzero = {0.f, 0.f, 0.f, 0.f};
#pragma unroll
    for (int i = 0; i < 2; i++)
#pragma unroll
        for (int j = 0; j < 4; j++) acc[i][j] = fzero;

    for (int k0 = 0; k0 < Keff; k0 += 64) {
#pragma unroll
        for (int kc = 0; kc < 2; kc++) {
            const bf16* ga0 =
                A + (size_t)(m0 + wave * 16 + srow) * K + (k0 + kc * 32 + scol);
            const bf16* gb0 =
                B + (size_t)(n0 + wave * 16 + srow) * K + (k0 + kc * 32 + scol);
            gload_lds16(ga0,                  As[kc] + wave * 512);
            gload_lds16(ga0 + (size_t)64 * K, As[kc] + (wave + 4) * 512);
            gload_lds16(gb0,                  Bs[kc] + wave * 512);
        }
        __syncthreads();

        bf16x8 af[2][2], bfr[2][4];
#pragma unroll
        for (int kc = 0; kc < 2; kc++) {
#pragma unroll
            for (int i = 0; i < 2; i++)
                af[kc][i] = *(const bf16x8*)(As[kc] + (wm + i * 16 + lr) * 32 + lq * 8);
#pragma unroll
            for (int j = 0; j < 4; j++)
                bfr[kc][j] = *(const bf16x8*)(Bs[kc] + (j * 16 + lr) * 32 + lq * 8);
        }
#pragma unroll
        for (int kc = 0; kc < 2; kc++)
#pragma unroll
            for (int i = 0; i < 2; i++)
#pragma unroll
                for (int j = 0; j < 4; j++)
                    acc[i][j] = __builtin_amdgcn_mfma_f32_16x16x32_bf16(
                        af[kc][i], bfr[kc][j], acc[i][j], 0, 0, 0);
        __syncthreads();
    }

#pragma unroll
    for (int j = 0; j < 4; j++) {
        const int col = n0 + j * 16 + lr;
        const float bb = bias ? bias[col] : 0.0f;
#pragma unroll
        for (int i = 0; i < 2; i++) {
            const int rowb = m0 + wm + i * 16 + lq * 4;
#pragma unroll
            for (int r = 0; r < 4; r++) {
                if (EPI == 0)
                    ((bf16*)Cv)[(size_t)bz * sC + (size_t)(rowb + r) * N + col] =
                        (bf16)(acc[i][j][r] * scale + bb);
                else
                    ((float*)Cv)[(size_t)bz * sC + (size_t)(rowb + r) * N + col] =
                        acc[i][j][r] * scale + bb;
            }
        }
    }
}

// ---------------------------------------------------------------- softmax
// one block per row; S=2048; causal length L = q+1; bf16 scores in/probs out.
__global__ __launch_bounds__(256) void softmax_causal(
    const bf16* __restrict__ Sc, bf16* __restrict__ P, int S) {
    const int row = blockIdx.x;          // b*S + q
    const int q = row & (S - 1);
    const bf16* src = Sc + (size_t)row * S;
    bf16* dst = P + (size_t)row * S;
    const int L = q + 1;
    const int tid = threadIdx.x;

    float v[8];
    float mx = -3.0e38f;
#pragma unroll
    for (int i = 0; i < 4; i++) {
        int k = (i * 256 + tid) * 2;
        bf16x2 u = ((const bf16x2*)src)[i * 256 + tid];
        v[2 * i]     = (k < L)     ? (float)u.x : -3.0e38f;
        v[2 * i + 1] = (k + 1 < L) ? (float)u.y : -3.0e38f;
        mx = fmaxf(mx, fmaxf(v[2 * i], v[2 * i + 1]));
    }
#pragma unroll
    for (int off = 32; off > 0; off >>= 1) mx = fmaxf(mx, __shfl_xor(mx, off, 64));
    __shared__ float redm[4], reds[4];
    if ((tid & 63) == 0) redm[tid >> 6] = mx;
    __syncthreads();
    mx = fmaxf(fmaxf(redm[0], redm[1]), fmaxf(redm[2], redm[3]));

    float sum = 0.f;
#pragma unroll
    for (int i = 0; i < 8; i++) {
        float e = (v[i] > -1.0e38f) ? __expf(v[i] - mx) : 0.f;
        v[i] = e;
        sum += e;
    }
#pragma unroll
    for (int off = 32; off > 0; off >>= 1) sum += __shfl_xor(sum, off, 64);
    if ((tid & 63) == 0) reds[tid >> 6] = sum;
    __syncthreads();
    sum = reds[0] + reds[1] + reds[2] + reds[3];
    const float inv = 1.0f / sum;
#pragma unroll
    for (int i = 0; i < 4; i++) {
        bf16x2 o;
        o.x = (bf16)(v[2 * i] * inv);
        o.y = (bf16)(v[2 * i + 1] * inv);
        ((bf16x2*)dst)[i * 256 + tid] = o;
    }
}

// ---------------------------------------------------------------- launch
extern "C" void kernel_launch(void* const* d_in, const int* in_sizes, int n_in,
                              void* d_out, int out_size, void* d_ws, size_t ws_size,
                              hipStream_t stream) {
    const int B = 4, S = 2048, E = 1024;
    const size_t SBE = (size_t)B * S * E;   // 8,388,608
    const size_t EE = (size_t)E * E;        // 1,048,576

    const float* q_in = (const float*)d_in[0];
    const float* k_in = (const float*)d_in[1];
    const float* v_in = (const float*)d_in[2];
    // d_in[3] = mask (tril) — causality handled by index math
    const float* Wq = (const float*)d_in[4];
    const float* bq = (const float*)d_in[5];
    const float* Wk = (const float*)d_in[6];
    const float* bk = (const float*)d_in[7];
    const float* Wv = (const float*)d_in[8];
    const float* bv = (const float*)d_in[9];
    const float* Wo = (const float*)d_in[10];
    const float* bo = (const float*)d_in[11];

    char* ws = (char*)d_ws;
    // Region A (64 MB), time-multiplexed:
    //   phase 1: qb|kb|vb (48MB)  phase 2: Sc (bf16, 33.5MB)  phase 3: AO (16MB)
    bf16* qkvb = (bf16*)ws;
    bf16* Sc = (bf16*)ws;
    bf16* AO = (bf16*)ws;
    char* p = ws + (size_t)B * S * S * 4;
    bf16* QKVb = (bf16*)p; p += 3 * SBE * 2;   // Qb|Kb|Vb contiguous
    bf16* Vt = (bf16*)p; p += SBE * 2;
    bf16* Pb = (bf16*)p; p += (size_t)B * S * S * 2;
    bf16* Wb = (bf16*)p; p += 4 * EE * 2;      // Wq|Wk|Wv|Wo contiguous
    float* biasWS = (float*)p; p += 3 * E * 4; // bq|bk|bv contiguous

    bf16* Qb = QKVb;
    bf16* Vb = QKVb + 2 * SBE;
    bf16* Wob = Wb + 3 * EE;

    // 1. converts + bias gather
    dim3 gcvt3((int)(SBE / 4 / 256), 1, 3);
    cvt3_f32_to_bf16<<<gcvt3, 256, 0, stream>>>(q_in, k_in, v_in, qkvb, (int)(SBE / 4));
    dim3 gcvt4((int)(EE / 4 / 256), 1, 4);
    cvt4_f32_to_bf16<<<gcvt4, 256, 0, stream>>>(Wq, Wk, Wv, Wo, Wb, (int)(EE / 4));
    hipMemcpyAsync(biasWS,         bq, E * 4, hipMemcpyDeviceToDevice, stream);
    hipMemcpyAsync(biasWS + E,     bk, E * 4, hipMemcpyDeviceToDevice, stream);
    hipMemcpyAsync(biasWS + 2 * E, bv, E * 4, hipMemcpyDeviceToDevice, stream);

    dim3 blk(256);
    // 2. fused QKV projection, 128x128 tiles, XCD-swizzled
    dim3 gproj(E / 128, (B * S) / 128, 3);
    gemm_bt128<0><<<gproj, blk, 0, stream>>>(qkvb, Wb, biasWS, QKVb,
                                             B * S, E, E,
                                             (long long)SBE, (long long)EE,
                                             (long long)SBE, (long long)E, 1.f);

    // 3. V^T per batch: [S,E] -> [E,S]
    dim3 gt(E / 64, S / 64, B);
    transpose_bf16<<<gt, blk, 0, stream>>>((const unsigned short*)Vb,
                                           (unsigned short*)Vt, S, E);

    // 4. scores = Q K^T / 32 -> bf16, skip tiles above diagonal
    dim3 gsc(S / 64, S / 128, B);
    gemm_bt64<0><<<gsc, blk, 0, stream>>>(Qb, QKVb + SBE, nullptr, Sc, S, S, E,
                                          (long long)S * E, (long long)S * E,
                                          (long long)S * S, 0, 0.03125f, 1);

    // 5. causal softmax -> bf16 probs (zeros above diagonal)
    softmax_causal<<<B * S, 256, 0, stream>>>(Sc, Pb, S);

    // 6. AO = P @ V (via Vt), K trimmed causally
    dim3 gpv(E / 64, S / 128, B);
    gemm_bt64<0><<<gpv, blk, 0, stream>>>(Pb, Vt, nullptr, AO, S, E, S,
                                          (long long)S * S, (long long)E * S,
                                          (long long)S * E, 0, 1.f, 2);

    // 7. out = AO @ Wo^T + bo, fp32
    dim3 gout(E / 64, (B * S) / 128, 1);
    gemm_bt64<1><<<gout, blk, 0, stream>>>(AO, Wob, bo, (float*)d_out,
                                           B * S, E, E, 0, 0, 0, 0, 1.f, 0);
}

// Round 6
// 419.332 us; speedup vs baseline: 1.1168x; 1.0056x over previous
//
#include <hip/hip_runtime.h>

typedef __bf16 bf16;
typedef __attribute__((ext_vector_type(8))) __bf16 bf16x8;
typedef __attribute__((ext_vector_type(4))) __bf16 bf16x4;
typedef __attribute__((ext_vector_type(2))) __bf16 bf16x2;
typedef __attribute__((ext_vector_type(4))) float f32x4;

#define DEVINL __device__ __forceinline__

// Async global->LDS, 16B per lane. LDS dst must be the wave-uniform base;
// lane l's global data lands at base + l*16.
DEVINL void gload_lds16(const bf16* g, bf16* l) {
    __builtin_amdgcn_global_load_lds(
        (__attribute__((address_space(1))) unsigned int*)(unsigned long long)g,
        (__attribute__((address_space(3))) unsigned int*)l,
        16, 0, 0);
}

// XCD-aware swizzle: block->XCD is (linear id % 8). Give each XCD a
// contiguous by-slab with bx fastest so same-A blocks share one L2.
// Requires gridDim.y % 8 == 0.
DEVINL void xcd_swizzle(int& bx, int& by) {
    const int gx = gridDim.x, gy = gridDim.y;
    const int l = blockIdx.y * gx + blockIdx.x;
    const int xcd = l & 7;
    const int li = l >> 3;
    by = xcd * (gy >> 3) + li / gx;
    bx = li - (li / gx) * gx;
}

// LDS XOR swizzle:
//   writer lane l fetches global col-chunk ((l&3) ^ ((l>>3)&3))  [16B chunks]
//   reader for tile row R, wanted chunk lq reads physical chunk lq ^ ((R>>1)&3)
// -> frag reads become 2-way bank aliasing (free) instead of 8-way.

// ---------------------------------------------------------------- converts
__global__ __launch_bounds__(256) void cvt3_f32_to_bf16(
    const float* __restrict__ a, const float* __restrict__ b,
    const float* __restrict__ c, bf16* __restrict__ out, int n4) {
    int i = blockIdx.x * blockDim.x + threadIdx.x;
    if (i >= n4) return;
    const float* src = (blockIdx.z == 0) ? a : (blockIdx.z == 1) ? b : c;
    bf16* dst = out + (size_t)blockIdx.z * (size_t)n4 * 4;
    float4 f = ((const float4*)src)[i];
    bf16x4 o;
    o.x = (bf16)f.x; o.y = (bf16)f.y; o.z = (bf16)f.z; o.w = (bf16)f.w;
    ((bf16x4*)dst)[i] = o;
}

__global__ __launch_bounds__(256) void cvt4_f32_to_bf16(
    const float* __restrict__ a, const float* __restrict__ b,
    const float* __restrict__ c, const float* __restrict__ d,
    bf16* __restrict__ out, int n4) {
    int i = blockIdx.x * blockDim.x + threadIdx.x;
    if (i >= n4) return;
    const float* src = (blockIdx.z == 0) ? a : (blockIdx.z == 1) ? b
                     : (blockIdx.z == 2) ? c : d;
    bf16* dst = out + (size_t)blockIdx.z * (size_t)n4 * 4;
    float4 f = ((const float4*)src)[i];
    bf16x4 o;
    o.x = (bf16)f.x; o.y = (bf16)f.y; o.z = (bf16)f.z; o.w = (bf16)f.w;
    ((bf16x4*)dst)[i] = o;
}

// ---------------------------------------------------------------- transpose
__global__ __launch_bounds__(256) void transpose_bf16(
    const unsigned short* __restrict__ in, unsigned short* __restrict__ out,
    int R, int C) {
    __shared__ unsigned short t[64][65];
    const size_t bo = (size_t)blockIdx.z * R * C;
    const int r0 = blockIdx.y * 64, c0 = blockIdx.x * 64;
#pragma unroll
    for (int i = 0; i < 16; i++) {
        int lin = threadIdx.x + i * 256;
        int r = lin >> 6, c = lin & 63;
        t[r][c] = in[bo + (size_t)(r0 + r) * C + (c0 + c)];
    }
    __syncthreads();
#pragma unroll
    for (int i = 0; i < 16; i++) {
        int lin = threadIdx.x + i * 256;
        int r = lin >> 6, c = lin & 63;
        out[bo + (size_t)(c0 + r) * R + (r0 + c)] = t[c][r];
    }
}

// ------------------------------- GEMM 128x128, BK=32, dbuf + LDS-XOR swizzle
template <int EPI>
__global__ __launch_bounds__(256) void gemm_bt128(
    const bf16* __restrict__ A, const bf16* __restrict__ B,
    const float* __restrict__ bias0, const float* __restrict__ bias1,
    const float* __restrict__ bias2, void* __restrict__ Cv,
    int M, int N, int K,
    long long sA, long long sB, long long sC,
    float scale) {
    int bx, by;
    xcd_swizzle(bx, by);
    const int bz = blockIdx.z;
    const int m0 = by * 128, n0 = bx * 128;

    A += (size_t)bz * sA;
    B += (size_t)bz * sB;
    const float* bias = (bz == 0) ? bias0 : (bz == 1) ? bias1 : bias2;

    __shared__ __align__(16) bf16 As[2][128 * 32];
    __shared__ __align__(16) bf16 Bs[2][128 * 32];

    const int tid = threadIdx.x;
    const int wave = tid >> 6;
    const int lane = tid & 63;
    const int lr = lane & 15;
    const int lq = lane >> 4;
    const int wm = (wave >> 1) * 64;
    const int wn = (wave & 1) * 64;
    const int srow = lane >> 2;
    const int scol = ((lane & 3) ^ ((lane >> 3) & 3)) * 8;

    const bf16* gA = A + (size_t)(m0 + wave * 16 + srow) * K + scol;
    const bf16* gB = B + (size_t)(n0 + wave * 16 + srow) * K + scol;
    const size_t rowskip = (size_t)64 * K;
    const int rsw = (lq ^ ((lr >> 1) & 3)) * 8;   // reader chunk offset (elems)

    f32x4 acc[4][4];
    const f32x4 fzero = {0.f, 0.f, 0.f, 0.f};
#pragma unroll
    for (int i = 0; i < 4; i++)
#pragma unroll
        for (int j = 0; j < 4; j++) acc[i][j] = fzero;

#define STAGE128(bufi)                                        \
    do {                                                      \
        gload_lds16(gA,           As[bufi] + wave * 512);     \
        gload_lds16(gA + rowskip, As[bufi] + (wave + 4) * 512); \
        gload_lds16(gB,           Bs[bufi] + wave * 512);     \
        gload_lds16(gB + rowskip, Bs[bufi] + (wave + 4) * 512); \
        gA += 32; gB += 32;                                   \
    } while (0)

    STAGE128(0);
    int cur = 0;
    for (int k0 = 0; k0 < K; k0 += 32) {
        __syncthreads();                 // drains loads issued one iter ago
        if (k0 + 32 < K) STAGE128(cur ^ 1);

        bf16x8 af[4], bfr[4];
#pragma unroll
        for (int i = 0; i < 4; i++)
            af[i] = *(const bf16x8*)(As[cur] + (wm + i * 16 + lr) * 32 + rsw);
#pragma unroll
        for (int j = 0; j < 4; j++)
            bfr[j] = *(const bf16x8*)(Bs[cur] + (wn + j * 16 + lr) * 32 + rsw);
#pragma unroll
        for (int i = 0; i < 4; i++)
#pragma unroll
            for (int j = 0; j < 4; j++)
                acc[i][j] = __builtin_amdgcn_mfma_f32_16x16x32_bf16(
                    af[i], bfr[j], acc[i][j], 0, 0, 0);
        cur ^= 1;
    }
#undef STAGE128

#pragma unroll
    for (int j = 0; j < 4; j++) {
        const int col = n0 + wn + j * 16 + lr;
        const float bb = bias ? bias[col] : 0.0f;
#pragma unroll
        for (int i = 0; i < 4; i++) {
            const int rowb = m0 + wm + i * 16 + lq * 4;
#pragma unroll
            for (int r = 0; r < 4; r++) {
                if (EPI == 0)
                    ((bf16*)Cv)[(size_t)bz * sC + (size_t)(rowb + r) * N + col] =
                        (bf16)(acc[i][j][r] * scale + bb);
                else
                    ((float*)Cv)[(size_t)bz * sC + (size_t)(rowb + r) * N + col] =
                        acc[i][j][r] * scale + bb;
            }
        }
    }
}

// ------------------------------- GEMM 128x64, BK=32, dbuf + LDS-XOR swizzle
// causal 1: skip tiles fully above diagonal; 2: trim K to m0+128 (PV).
template <int EPI>
__global__ __launch_bounds__(256) void gemm_bt64(
    const bf16* __restrict__ A, const bf16* __restrict__ B,
    const float* __restrict__ bias, void* __restrict__ Cv,
    int M, int N, int K,
    long long sA, long long sB, long long sC,
    float scale, int causal) {
    int bx, by;
    xcd_swizzle(bx, by);
    const int bz = blockIdx.z;
    const int m0 = by * 128, n0 = bx * 64;
    if (causal == 1 && n0 > m0 + 127) return;
    int Keff = K;
    if (causal == 2) { Keff = m0 + 128; if (Keff > K) Keff = K; }

    A += (size_t)bz * sA;
    B += (size_t)bz * sB;

    __shared__ __align__(16) bf16 As[2][128 * 32];
    __shared__ __align__(16) bf16 Bs[2][64 * 32];

    const int tid = threadIdx.x;
    const int wave = tid >> 6;
    const int lane = tid & 63;
    const int lr = lane & 15;
    const int lq = lane >> 4;
    const int wm = wave * 32;
    const int srow = lane >> 2;
    const int scol = ((lane & 3) ^ ((lane >> 3) & 3)) * 8;

    const bf16* gA = A + (size_t)(m0 + wave * 16 + srow) * K + scol;
    const bf16* gB = B + (size_t)(n0 + wave * 16 + srow) * K + scol;
    const size_t rowskip = (size_t)64 * K;
    const int rsw = (lq ^ ((lr >> 1) & 3)) * 8;

    f32x4 acc[2][4];
    const f32x4 fzero = {0.f, 0.f, 0.f, 0.f};
#pragma unroll
    for (int i = 0; i < 2; i++)
#pragma unroll
        for (int j = 0; j < 4; j++) acc[i][j] = fzero;

#define STAGE64(bufi)                                          \
    do {                                                       \
        gload_lds16(gA,           As[bufi] + wave * 512);      \
        gload_lds16(gA + rowskip, As[bufi] + (wave + 4) * 512); \
        gload_lds16(gB,           Bs[bufi] + wave * 512);      \
        gA += 32; gB += 32;                                    \
    } while (0)

    STAGE64(0);
    int cur = 0;
    for (int k0 = 0; k0 < Keff; k0 += 32) {
        __syncthreads();
        if (k0 + 32 < Keff) STAGE64(cur ^ 1);

        bf16x8 af[2], bfr[4];
#pragma unroll
        for (int i = 0; i < 2; i++)
            af[i] = *(const bf16x8*)(As[cur] + (wm + i * 16 + lr) * 32 + rsw);
#pragma unroll
        for (int j = 0; j < 4; j++)
            bfr[j] = *(const bf16x8*)(Bs[cur] + (j * 16 + lr) * 32 + rsw);
#pragma unroll
        for (int i = 0; i < 2; i++)
#pragma unroll
            for (int j = 0; j < 4; j++)
                acc[i][j] = __builtin_amdgcn_mfma_f32_16x16x32_bf16(
                    af[i], bfr[j], acc[i][j], 0, 0, 0);
        cur ^= 1;
    }
#undef STAGE64

#pragma unroll
    for (int j = 0; j < 4; j++) {
        const int col = n0 + j * 16 + lr;
        const float bb = bias ? bias[col] : 0.0f;
#pragma unroll
        for (int i = 0; i < 2; i++) {
            const int rowb = m0 + wm + i * 16 + lq * 4;
#pragma unroll
            for (int r = 0; r < 4; r++) {
                if (EPI == 0)
                    ((bf16*)Cv)[(size_t)bz * sC + (size_t)(rowb + r) * N + col] =
                        (bf16)(acc[i][j][r] * scale + bb);
                else
                    ((float*)Cv)[(size_t)bz * sC + (size_t)(rowb + r) * N + col] =
                        acc[i][j][r] * scale + bb;
            }
        }
    }
}

// ---------------------------------------------------------------- softmax
// one block per row; S=2048; causal length L = q+1; bf16 scores in/probs out.
__global__ __launch_bounds__(256) void softmax_causal(
    const bf16* __restrict__ Sc, bf16* __restrict__ P, int S) {
    const int row = blockIdx.x;          // b*S + q
    const int q = row & (S - 1);
    const bf16* src = Sc + (size_t)row * S;
    bf16* dst = P + (size_t)row * S;
    const int L = q + 1;
    const int tid = threadIdx.x;

    float v[8];
    float mx = -3.0e38f;
#pragma unroll
    for (int i = 0; i < 4; i++) {
        int k = (i * 256 + tid) * 2;
        bf16x2 u = ((const bf16x2*)src)[i * 256 + tid];
        v[2 * i]     = (k < L)     ? (float)u.x : -3.0e38f;
        v[2 * i + 1] = (k + 1 < L) ? (float)u.y : -3.0e38f;
        mx = fmaxf(mx, fmaxf(v[2 * i], v[2 * i + 1]));
    }
#pragma unroll
    for (int off = 32; off > 0; off >>= 1) mx = fmaxf(mx, __shfl_xor(mx, off, 64));
    __shared__ float redm[4], reds[4];
    if ((tid & 63) == 0) redm[tid >> 6] = mx;
    __syncthreads();
    mx = fmaxf(fmaxf(redm[0], redm[1]), fmaxf(redm[2], redm[3]));

    float sum = 0.f;
#pragma unroll
    for (int i = 0; i < 8; i++) {
        float e = (v[i] > -1.0e38f) ? __expf(v[i] - mx) : 0.f;
        v[i] = e;
        sum += e;
    }
#pragma unroll
    for (int off = 32; off > 0; off >>= 1) sum += __shfl_xor(sum, off, 64);
    if ((tid & 63) == 0) reds[tid >> 6] = sum;
    __syncthreads();
    sum = reds[0] + reds[1] + reds[2] + reds[3];
    const float inv = 1.0f / sum;
#pragma unroll
    for (int i = 0; i < 4; i++) {
        bf16x2 o;
        o.x = (bf16)(v[2 * i] * inv);
        o.y = (bf16)(v[2 * i + 1] * inv);
        ((bf16x2*)dst)[i * 256 + tid] = o;
    }
}

// ---------------------------------------------------------------- launch
extern "C" void kernel_launch(void* const* d_in, const int* in_sizes, int n_in,
                              void* d_out, int out_size, void* d_ws, size_t ws_size,
                              hipStream_t stream) {
    const int B = 4, S = 2048, E = 1024;
    const size_t SBE = (size_t)B * S * E;   // 8,388,608
    const size_t EE = (size_t)E * E;        // 1,048,576

    const float* q_in = (const float*)d_in[0];
    const float* k_in = (const float*)d_in[1];
    const float* v_in = (const float*)d_in[2];
    // d_in[3] = mask (tril) — causality handled by index math
    const float* Wq = (const float*)d_in[4];
    const float* bq = (const float*)d_in[5];
    const float* Wk = (const float*)d_in[6];
    const float* bk = (const float*)d_in[7];
    const float* Wv = (const float*)d_in[8];
    const float* bv = (const float*)d_in[9];
    const float* Wo = (const float*)d_in[10];
    const float* bo = (const float*)d_in[11];

    char* ws = (char*)d_ws;
    // Region A (64 MB), time-multiplexed:
    //   phase 1: qb|kb|vb (48MB)  phase 2: Sc (bf16, 33.5MB)  phase 3: AO (16MB)
    bf16* qkvb = (bf16*)ws;
    bf16* Sc = (bf16*)ws;
    bf16* AO = (bf16*)ws;
    char* p = ws + (size_t)B * S * S * 4;
    bf16* QKVb = (bf16*)p; p += 3 * SBE * 2;   // Qb|Kb|Vb contiguous
    bf16* Vt = (bf16*)p; p += SBE * 2;
    bf16* Pb = (bf16*)p; p += (size_t)B * S * S * 2;
    bf16* Wb = (bf16*)p; p += 4 * EE * 2;      // Wq|Wk|Wv|Wo contiguous

    bf16* Qb = QKVb;
    bf16* Vb = QKVb + 2 * SBE;
    bf16* Wob = Wb + 3 * EE;

    // 1. converts
    dim3 gcvt3((int)(SBE / 4 / 256), 1, 3);
    cvt3_f32_to_bf16<<<gcvt3, 256, 0, stream>>>(q_in, k_in, v_in, qkvb, (int)(SBE / 4));
    dim3 gcvt4((int)(EE / 4 / 256), 1, 4);
    cvt4_f32_to_bf16<<<gcvt4, 256, 0, stream>>>(Wq, Wk, Wv, Wo, Wb, (int)(EE / 4));

    dim3 blk(256);
    // 2. fused QKV projection, 128x128 tiles, XCD-swizzled, dbuf
    dim3 gproj(E / 128, (B * S) / 128, 3);
    gemm_bt128<0><<<gproj, blk, 0, stream>>>(qkvb, Wb, bq, bk, bv, QKVb,
                                             B * S, E, E,
                                             (long long)SBE, (long long)EE,
                                             (long long)SBE, 1.f);

    // 3. V^T per batch: [S,E] -> [E,S]
    dim3 gt(E / 64, S / 64, B);
    transpose_bf16<<<gt, blk, 0, stream>>>((const unsigned short*)Vb,
                                           (unsigned short*)Vt, S, E);

    // 4. scores = Q K^T / 32 -> bf16, skip tiles above diagonal
    dim3 gsc(S / 64, S / 128, B);
    gemm_bt64<0><<<gsc, blk, 0, stream>>>(Qb, QKVb + SBE, nullptr, Sc, S, S, E,
                                          (long long)S * E, (long long)S * E,
                                          (long long)S * S, 0.03125f, 1);

    // 5. causal softmax -> bf16 probs (zeros above diagonal)
    softmax_causal<<<B * S, 256, 0, stream>>>(Sc, Pb, S);

    // 6. AO = P @ V (via Vt), K trimmed causally
    dim3 gpv(E / 64, S / 128, B);
    gemm_bt64<0><<<gpv, blk, 0, stream>>>(Pb, Vt, nullptr, AO, S, E, S,
                                          (long long)S * S, (long long)E * S,
                                          (long long)S * E, 1.f, 2);

    // 7. out = AO @ Wo^T + bo, fp32
    dim3 gout(E / 64, (B * S) / 128, 1);
    gemm_bt64<1><<<gout, blk, 0, stream>>>(AO, Wob, bo, (float*)d_out,
                                           B * S, E, E, 0, 0, 0, 1.f, 0);
}